// Round 5
// baseline (271.694 us; speedup 1.0000x reference)
//
#include <hip/hip_runtime.h>

// dense_image_warp: out[b,h,w,c] = bilinear(img, h - flow[b,h,w,0], w - flow[b,h,w,1])
// tfa semantics: floor clipped to [0, size-2], alpha clipped to [0,1].
// B=8, H=512, W=512, C=16 (fp32).
//
// Round-5: XCD-aware block swizzle, no warm pass.
// Evidence: R4 showed an L3-resident gather costs ~68us vs 91us HBM-order,
// but a separate warm pass costs the difference. Root cause of the bad HBM
// order: linear mapping gives block j row-pair j/8, column-chunk j%8, so
// round-robin block->XCD dispatch hands each XCD one column-chunk of EVERY
// row of ALL images (whole-144MB footprint per XCD, ~0.93 TB/s random reads).
// swz = (bid&7)*2048 + (bid>>3) gives XCD i exactly image i (18 MB), rows in
// order: live window ~40 rows (flow ~ N(0,5)) = 1.3 MB << 4 MB per-XCD L2.
// Corner reuse is then L2-served and HBM misses arrive page-local.
// nt stores keep the 131 MB write stream from evicting the L2 window.

constexpr int B = 8;
constexpr int H = 512;
constexpr int W = 512;
constexpr int C = 16;

typedef float f32x4 __attribute__((ext_vector_type(4)));

__global__ __launch_bounds__(256) void warp_kernel(
    const float* __restrict__ img,
    const float* __restrict__ flow,
    float* __restrict__ out)
{
    // --- XCD-aware swizzle: grid = 16384 = 8 XCDs x 2048, bijective ---
    // XCD of a block is (hw round-robin) blockIdx.x % 8; give XCD i the
    // contiguous work range [i*2048, (i+1)*2048) = image i, rows ascending.
    const int bid = blockIdx.x;
    const int swz = (bid & 7) * 2048 + (bid >> 3);

    const int tid = swz * 256 + (int)threadIdx.x;
    const int g  = tid >> 2;          // vertical pixel-pair index
    const int c0 = (tid & 3) << 2;    // channel offset: 0,4,8,12

    // g -> (b, hh, w) with hh in [0, H/2); pair rows h0 = 2*hh, h0+1
    const int w  = g & (W - 1);
    const int hh = (g >> 9) & (H / 2 - 1);
    const int b  = g >> 17;
    const int h0 = hh << 1;

    const int p0 = (b * H + h0) * W + w;   // pixel (b, h0,   w)
    const int p1 = p0 + W;                 // pixel (b, h0+1, w)

    const float2 f0 = *reinterpret_cast<const float2*>(flow + 2 * (size_t)p0);
    const float2 f1 = *reinterpret_cast<const float2*>(flow + 2 * (size_t)p1);

    // --- pixel 0 address math ---
    const float qy0 = (float)h0 - f0.x;
    const float qx0 = (float)w  - f0.y;
    const float fy0 = fminf(fmaxf(floorf(qy0), 0.0f), (float)(H - 2));
    const float fx0 = fminf(fmaxf(floorf(qx0), 0.0f), (float)(W - 2));
    const float ay0 = fminf(fmaxf(qy0 - fy0, 0.0f), 1.0f);
    const float ax0 = fminf(fmaxf(qx0 - fx0, 0.0f), 1.0f);
    const int iy0 = (int)fy0;
    const int ix0 = (int)fx0;

    // --- pixel 1 address math ---
    const float qy1 = (float)(h0 + 1) - f1.x;
    const float qx1 = (float)w        - f1.y;
    const float fy1 = fminf(fmaxf(floorf(qy1), 0.0f), (float)(H - 2));
    const float fx1 = fminf(fmaxf(floorf(qx1), 0.0f), (float)(W - 2));
    const float ay1 = fminf(fmaxf(qy1 - fy1, 0.0f), 1.0f);
    const float ax1 = fminf(fmaxf(qx1 - fx1, 0.0f), 1.0f);
    const int iy1 = (int)fy1;
    const int ix1 = (int)fx1;

    const int rowStride = W * C;  // floats per image row
    const float* base0 = img + ((size_t)((b * H + iy0) * W + ix0) * C + c0);
    const float* base1 = img + ((size_t)((b * H + iy1) * W + ix1) * C + c0);

    const f32x4 tl0 = *reinterpret_cast<const f32x4*>(base0);
    const f32x4 tr0 = *reinterpret_cast<const f32x4*>(base0 + C);
    const f32x4 bl0 = *reinterpret_cast<const f32x4*>(base0 + rowStride);
    const f32x4 br0 = *reinterpret_cast<const f32x4*>(base0 + rowStride + C);
    const f32x4 tl1 = *reinterpret_cast<const f32x4*>(base1);
    const f32x4 tr1 = *reinterpret_cast<const f32x4*>(base1 + C);
    const f32x4 bl1 = *reinterpret_cast<const f32x4*>(base1 + rowStride);
    const f32x4 br1 = *reinterpret_cast<const f32x4*>(base1 + rowStride + C);

    // Reference op order, elementwise.
    const f32x4 t0  = tl0 + ax0 * (tr0 - tl0);
    const f32x4 bo0 = bl0 + ax0 * (br0 - bl0);
    const f32x4 o0  = t0 + ay0 * (bo0 - t0);

    const f32x4 t1  = tl1 + ax1 * (tr1 - tl1);
    const f32x4 bo1 = bl1 + ax1 * (br1 - bl1);
    const f32x4 o1  = t1 + ay1 * (bo1 - t1);

    // nt: keep the write stream out of the (now-precious) L2 window.
    __builtin_nontemporal_store(
        o0, reinterpret_cast<f32x4*>(out + (size_t)p0 * C + c0));
    __builtin_nontemporal_store(
        o1, reinterpret_cast<f32x4*>(out + (size_t)p1 * C + c0));
}

extern "C" void kernel_launch(void* const* d_in, const int* in_sizes, int n_in,
                              void* d_out, int out_size, void* d_ws, size_t ws_size,
                              hipStream_t stream) {
    const float* img  = (const float*)d_in[0];   // [B,H,W,C] fp32
    const float* flow = (const float*)d_in[1];   // [B,H,W,2] fp32
    float* out = (float*)d_out;                  // [B,H,W,C] fp32

    // 2 pixels per thread, 4 lanes per pixel:
    // total threads = B*(H/2)*W*4 = 4,194,304 -> grid 16384 (divisible by 8)
    const int total = B * (H / 2) * W * 4;
    const int block = 256;
    const int grid = total / block;  // 16384
    warp_kernel<<<grid, block, 0, stream>>>(img, flow, out);
}

// Round 7
// 251.829 us; speedup vs baseline: 1.0789x; 1.0789x over previous
//
#include <hip/hip_runtime.h>

// dense_image_warp: out[b,h,w,c] = bilinear(img, h - flow[b,h,w,0], w - flow[b,h,w,1])
// tfa semantics: floor clipped to [0, size-2], alpha clipped to [0,1].
// B=8, H=512, W=512, C=16 (fp32).
//
// FINAL (round-3 best, 90.5 us/dispatch, 251.5 us bench). Session evidence:
//  - R1 octet restructuring: -10%. R2 nt stores: null. R3 2x MLP: null.
//  - R4 L3-prewarm: gather floor 68 us even fully L3-resident; warm(25)+68 = 93
//    == direct 91 -> scattered-service-rate bound, not byte-location bound.
//  - R5 XCD swizzle: FETCH down 13%, dur UP 15% (DRAM parallelism loss).
// flow is i.i.d. 5*N(0,1): corner reads are random within a +/-20 px window,
// so LDS tiling needs R>=16 halo -> >=3x streaming overfetch -> computes to
// >= current time. This access pattern is at the machine's scattered 64-B
// gather service roofline (~90 us); all pipes idle in counters by design.
//
// Structure: 2 vertically-adjacent pixels per thread, 4 lanes per pixel
// (float4 channels chunk). Flow loads then 8 corner gathers all in flight;
// coalesced 1-KB/wave nt stores.
// (R6 bench attempt failed on container infra; resubmitting unchanged.)

constexpr int B = 8;
constexpr int H = 512;
constexpr int W = 512;
constexpr int C = 16;

typedef float f32x4 __attribute__((ext_vector_type(4)));

__global__ __launch_bounds__(256) void warp_kernel(
    const float* __restrict__ img,
    const float* __restrict__ flow,
    float* __restrict__ out)
{
    const int tid = blockIdx.x * blockDim.x + threadIdx.x;
    const int g  = tid >> 2;          // vertical pixel-pair index
    const int c0 = (tid & 3) << 2;    // channel offset: 0,4,8,12

    // g -> (b, hh, w) with hh in [0, H/2); pair rows h0 = 2*hh, h0+1
    const int w  = g & (W - 1);
    const int hh = (g >> 9) & (H / 2 - 1);
    const int b  = g >> 17;
    const int h0 = hh << 1;

    const int p0 = (b * H + h0) * W + w;   // pixel (b, h0,   w)
    const int p1 = p0 + W;                 // pixel (b, h0+1, w)

    // Two independent flow loads -> both in flight together.
    const float2 f0 = *reinterpret_cast<const float2*>(flow + 2 * (size_t)p0);
    const float2 f1 = *reinterpret_cast<const float2*>(flow + 2 * (size_t)p1);

    // --- pixel 0 address math ---
    const float qy0 = (float)h0 - f0.x;
    const float qx0 = (float)w  - f0.y;
    const float fy0 = fminf(fmaxf(floorf(qy0), 0.0f), (float)(H - 2));
    const float fx0 = fminf(fmaxf(floorf(qx0), 0.0f), (float)(W - 2));
    const float ay0 = fminf(fmaxf(qy0 - fy0, 0.0f), 1.0f);
    const float ax0 = fminf(fmaxf(qx0 - fx0, 0.0f), 1.0f);
    const int iy0 = (int)fy0;
    const int ix0 = (int)fx0;

    // --- pixel 1 address math ---
    const float qy1 = (float)(h0 + 1) - f1.x;
    const float qx1 = (float)w        - f1.y;
    const float fy1 = fminf(fmaxf(floorf(qy1), 0.0f), (float)(H - 2));
    const float fx1 = fminf(fmaxf(floorf(qx1), 0.0f), (float)(W - 2));
    const float ay1 = fminf(fmaxf(qy1 - fy1, 0.0f), 1.0f);
    const float ax1 = fminf(fmaxf(qx1 - fx1, 0.0f), 1.0f);
    const int iy1 = (int)fy1;
    const int ix1 = (int)fx1;

    const int rowStride = W * C;  // floats per image row
    const float* base0 = img + ((size_t)((b * H + iy0) * W + ix0) * C + c0);
    const float* base1 = img + ((size_t)((b * H + iy1) * W + ix1) * C + c0);

    // 8 independent corner gathers -> all in flight together.
    const f32x4 tl0 = *reinterpret_cast<const f32x4*>(base0);
    const f32x4 tr0 = *reinterpret_cast<const f32x4*>(base0 + C);
    const f32x4 bl0 = *reinterpret_cast<const f32x4*>(base0 + rowStride);
    const f32x4 br0 = *reinterpret_cast<const f32x4*>(base0 + rowStride + C);
    const f32x4 tl1 = *reinterpret_cast<const f32x4*>(base1);
    const f32x4 tr1 = *reinterpret_cast<const f32x4*>(base1 + C);
    const f32x4 bl1 = *reinterpret_cast<const f32x4*>(base1 + rowStride);
    const f32x4 br1 = *reinterpret_cast<const f32x4*>(base1 + rowStride + C);

    // Reference op order, elementwise.
    const f32x4 t0  = tl0 + ax0 * (tr0 - tl0);
    const f32x4 bo0 = bl0 + ax0 * (br0 - bl0);
    const f32x4 o0  = t0 + ay0 * (bo0 - t0);

    const f32x4 t1  = tl1 + ax1 * (tr1 - tl1);
    const f32x4 bo1 = bl1 + ax1 * (br1 - bl1);
    const f32x4 o1  = t1 + ay1 * (bo1 - t1);

    __builtin_nontemporal_store(
        o0, reinterpret_cast<f32x4*>(out + (size_t)p0 * C + c0));
    __builtin_nontemporal_store(
        o1, reinterpret_cast<f32x4*>(out + (size_t)p1 * C + c0));
}

extern "C" void kernel_launch(void* const* d_in, const int* in_sizes, int n_in,
                              void* d_out, int out_size, void* d_ws, size_t ws_size,
                              hipStream_t stream) {
    const float* img  = (const float*)d_in[0];   // [B,H,W,C] fp32
    const float* flow = (const float*)d_in[1];   // [B,H,W,2] fp32
    float* out = (float*)d_out;                  // [B,H,W,C] fp32

    // 2 pixels per thread, 4 lanes per pixel:
    // total threads = B*(H/2)*W*4 = 4,194,304 -> exact fit
    const int total = B * (H / 2) * W * 4;
    const int block = 256;
    const int grid = total / block;  // 16384
    warp_kernel<<<grid, block, 0, stream>>>(img, flow, out);
}